// Round 3
// baseline (1692.814 us; speedup 1.0000x reference)
//
#include <hip/hip_runtime.h>

#define N_NODES 100000
#define N_EDGES 3200000
#define NOUT 6

#define NPB 256                                   // nodes per bucket
#define NBUK ((N_NODES + NPB - 1) / NPB)          // 391
#define PCHUNK 4096                               // edges per partition block
#define PNB ((N_EDGES + PCHUNK - 1) / PCHUNK)     // 782

// ---------------- small zero ----------------
__global__ __launch_bounds__(512) void k_zero512(int* __restrict__ p) {
    p[threadIdx.x] = 0;
}

// ---------------- coarse histogram of target buckets ----------------
__global__ __launch_bounds__(256) void k_coarse_hist(const int* __restrict__ col,
                                                     int* __restrict__ gcounts) {
    __shared__ int h[512];
    const int t = threadIdx.x;
    for (int i = t; i < 512; i += 256) h[i] = 0;
    __syncthreads();
    for (int e = blockIdx.x * 256 + t; e < N_EDGES; e += 1024 * 256)
        atomicAdd(&h[col[e] >> 8], 1);
    __syncthreads();
    for (int i = t; i < 512; i += 256)
        if (h[i]) atomicAdd(&gcounts[i], h[i]);
}

// ---------------- scan bucket counts -> bbase, gcursor ----------------
__global__ __launch_bounds__(512) void k_coarse_scan(const int* __restrict__ gcounts,
                                                     int* __restrict__ bbase,
                                                     int* __restrict__ gcursor) {
    __shared__ int s[512];
    const int t = threadIdx.x;
    int v = (t < NBUK) ? gcounts[t] : 0;
    s[t] = v;
    __syncthreads();
    for (int off = 1; off < 512; off <<= 1) {
        int u = (t >= off) ? s[t - off] : 0;
        __syncthreads();
        s[t] += u;
        __syncthreads();
    }
    int excl = s[t] - v;
    if (t < NBUK) { bbase[t] = excl; gcursor[t] = excl; }
    if (t == 0) bbase[NBUK] = N_EDGES;
}

// ---------------- LDS-staged bucket partition ----------------
__global__ __launch_bounds__(512) void k_partition(const int* __restrict__ row,
                                                   const int* __restrict__ col,
                                                   int* __restrict__ gcursor,
                                                   int* __restrict__ bedge) {
    __shared__ int hist[512];
    __shared__ int lstart[512];
    __shared__ int lcur[512];
    __shared__ int gbase[512];
    __shared__ int sscan[512];
    __shared__ int stage[PCHUNK];
    __shared__ unsigned short stageb[PCHUNK];

    const int t = threadIdx.x;
    const int c0 = blockIdx.x * PCHUNK;
    int cnt = N_EDGES - c0; if (cnt > PCHUNK) cnt = PCHUNK;

    hist[t] = 0; lcur[t] = 0;
    __syncthreads();

    int myp[8]; int myb[8];
#pragma unroll
    for (int i = 0; i < 8; ++i) {
        int p = i * 512 + t;
        myb[i] = -1;
        if (p < cnt) {
            int e = c0 + p;
            int c = col[e], r = row[e];
            int b = c >> 8;
            myp[i] = ((c & 255) << 17) | r;
            myb[i] = b;
            atomicAdd(&hist[b], 1);
        }
    }
    __syncthreads();

    int hv = hist[t];
    sscan[t] = hv;
    __syncthreads();
    for (int off = 1; off < 512; off <<= 1) {
        int u = (t >= off) ? sscan[t - off] : 0;
        __syncthreads();
        sscan[t] += u;
        __syncthreads();
    }
    lstart[t] = sscan[t] - hv;
    if (t < NBUK && hv > 0) gbase[t] = atomicAdd(&gcursor[t], hv);
    __syncthreads();

#pragma unroll
    for (int i = 0; i < 8; ++i) {
        if (myb[i] >= 0) {
            int pos = lstart[myb[i]] + atomicAdd(&lcur[myb[i]], 1);
            stage[pos] = myp[i];
            stageb[pos] = (unsigned short)myb[i];
        }
    }
    __syncthreads();

    for (int p = t; p < cnt; p += 512) {
        int b = stageb[p];
        bedge[gbase[b] + p - lstart[b]] = stage[p];
    }
}

// ---------------- per-bucket degree -> dinv ----------------
__global__ __launch_bounds__(256) void k_bucket_dinv(const int* __restrict__ bbase,
                                                     const int* __restrict__ bedge,
                                                     float* __restrict__ dinv) {
    __shared__ int cnt[NPB];
    const int t = threadIdx.x;
    const int b = blockIdx.x;
    cnt[t] = 0;
    __syncthreads();
    int s = bbase[b], e = bbase[b + 1];
    for (int j = s + t; j < e; j += 256) atomicAdd(&cnt[bedge[j] >> 17], 1);
    __syncthreads();
    int g = b * NPB + t;
    if (g < N_NODES) dinv[g] = rsqrtf((float)cnt[t] + 1.0f);
}

// ---------------- layer 1 GEMM: hs1 = (x @ W1) * dinv ----------------
__global__ __launch_bounds__(256) void k_gemm1(const float* __restrict__ x,
                                               const float* __restrict__ W1,
                                               const float* __restrict__ dinv,
                                               float* __restrict__ hs1) {
    __shared__ float Ws[64 * 64];
    __shared__ float Xs[64 * 65];
    const int tx = threadIdx.x;
    const int nodeBase = blockIdx.x * 64;

    for (int t = tx; t < 64 * 64; t += 256) Ws[t] = W1[t];

    for (int t = tx; t < 64 * 16; t += 256) {
        int r = t >> 4, c4 = t & 15;
        int g = nodeBase + r;
        float4 v = make_float4(0.f, 0.f, 0.f, 0.f);
        if (g < N_NODES) v = reinterpret_cast<const float4*>(x)[g * 16 + c4];
        float* p = &Xs[r * 65 + c4 * 4];
        p[0] = v.x; p[1] = v.y; p[2] = v.z; p[3] = v.w;
    }
    __syncthreads();

    const int nG = tx >> 4;
    const int cG = tx & 15;
    float acc[4][4] = {};
    for (int k = 0; k < 64; ++k) {
        float4 w = *reinterpret_cast<const float4*>(&Ws[k * 64 + cG * 4]);
#pragma unroll
        for (int i = 0; i < 4; ++i) {
            float xv = Xs[(nG * 4 + i) * 65 + k];
            acc[i][0] = fmaf(xv, w.x, acc[i][0]);
            acc[i][1] = fmaf(xv, w.y, acc[i][1]);
            acc[i][2] = fmaf(xv, w.z, acc[i][2]);
            acc[i][3] = fmaf(xv, w.w, acc[i][3]);
        }
    }

#pragma unroll
    for (int i = 0; i < 4; ++i) {
        int n = nodeBase + nG * 4 + i;
        if (n < N_NODES) {
            float dv = dinv[n];
            float4 o = make_float4(acc[i][0] * dv, acc[i][1] * dv, acc[i][2] * dv, acc[i][3] * dv);
            reinterpret_cast<float4*>(hs1)[n * 16 + cG] = o;
        }
    }
}

// ---------------- bucket aggregation layer 1 (LDS accumulator) ----------------
__global__ __launch_bounds__(512, 2) void k_agg1b(const int* __restrict__ bbase,
                                                  const int* __restrict__ bedge,
                                                  const float* __restrict__ hs1,
                                                  float* __restrict__ agg1) {
    __shared__ float acc[NPB * 64];   // 64 KB
    const int t = threadIdx.x, w = t >> 6, lane = t & 63;
    const int b = blockIdx.x;
    const int nbase = b * NPB;

    for (int n = w; n < NPB; n += 8) {
        int g = nbase + n;
        acc[n * 64 + lane] = (g < N_NODES) ? hs1[g * 64 + lane] : 0.f;   // self-loop term
    }
    __syncthreads();

    const int s = bbase[b], e = bbase[b + 1];
    for (int jb = s + w * 64; jb < e; jb += 8 * 64) {
        int c = e - jb; if (c > 64) c = 64;
        int v = bedge[jb + (lane < c ? lane : c - 1)];
        if (c == 64) {
#pragma unroll
            for (int k0 = 0; k0 < 64; k0 += 8) {
                float a[8]; int lc[8];
#pragma unroll
                for (int kk = 0; kk < 8; ++kk) {
                    int pk = __shfl(v, k0 + kk, 64);
                    lc[kk] = pk >> 17;
                    a[kk] = hs1[(pk & 0x1FFFF) * 64 + lane];
                }
#pragma unroll
                for (int kk = 0; kk < 8; ++kk)
                    atomicAdd(&acc[lc[kk] * 64 + lane], a[kk]);
            }
        } else {
            for (int k = 0; k < c; ++k) {
                int pk = __shfl(v, k, 64);
                atomicAdd(&acc[(pk >> 17) * 64 + lane], hs1[(pk & 0x1FFFF) * 64 + lane]);
            }
        }
    }
    __syncthreads();

    for (int n = w; n < NPB; n += 8) {
        int g = nbase + n;
        if (g < N_NODES) agg1[g * 64 + lane] = acc[n * 64 + lane];
    }
}

// ---------------- layer 2 fused: h1 = relu(dinv*agg1 + b1); hs2 = (h1@W2)*dinv ----------------
__global__ __launch_bounds__(128) void k_layer2(const float* __restrict__ agg1,
                                                const float* __restrict__ W2,
                                                const float* __restrict__ b1,
                                                const float* __restrict__ dinv,
                                                float* __restrict__ hs2) {
    __shared__ float W2s[64][8];
    __shared__ float b1s[64];
    __shared__ float Xs[128][65];
    const int tx = threadIdx.x;
    if (tx < 64) b1s[tx] = b1[tx];
    for (int t = tx; t < 64 * NOUT; t += 128) W2s[t / NOUT][t % NOUT] = W2[t];

    const int nodeBase = blockIdx.x * 128;
    for (int t = tx; t < 128 * 16; t += 128) {
        int r = t >> 4, c4 = t & 15;
        int g = nodeBase + r;
        float4 v = make_float4(0.f, 0.f, 0.f, 0.f);
        if (g < N_NODES) v = reinterpret_cast<const float4*>(agg1)[g * 16 + c4];
        float* p = &Xs[r][c4 * 4];
        p[0] = v.x; p[1] = v.y; p[2] = v.z; p[3] = v.w;
    }
    __syncthreads();

    int n = nodeBase + tx;
    if (n >= N_NODES) return;
    float dv = dinv[n];
    float acc[NOUT] = {};
    for (int k = 0; k < 64; ++k) {
        float hv = fmaxf(fmaf(dv, Xs[tx][k], b1s[k]), 0.f);
#pragma unroll
        for (int j = 0; j < NOUT; ++j) acc[j] = fmaf(hv, W2s[k][j], acc[j]);
    }
    float* o1 = hs2 + n * 8;
#pragma unroll
    for (int j = 0; j < NOUT; ++j) o1[j] = acc[j] * dv;
    o1[6] = 0.f; o1[7] = 0.f;   // padding channels read by k_agg2b
}

// ---------------- bucket aggregation layer 2 ----------------
__global__ __launch_bounds__(512) void k_agg2b(const int* __restrict__ bbase,
                                               const int* __restrict__ bedge,
                                               const float* __restrict__ hs2,
                                               float* __restrict__ agg2) {
    __shared__ float acc2[NPB * 8];   // 8 KB
    const int t = threadIdx.x, w = t >> 6, lane = t & 63;
    const int slot = lane >> 3, chan = lane & 7;
    const int b = blockIdx.x;
    const int nbase = b * NPB;

    for (int i = t; i < NPB * 8; i += 512) {
        int g8 = nbase * 8 + i;
        acc2[i] = (g8 < N_NODES * 8) ? hs2[g8] : 0.f;   // self-loop term
    }
    __syncthreads();

    const int s = bbase[b], e = bbase[b + 1];
    for (int jb = s + w * 64; jb < e; jb += 8 * 64) {
        int c = e - jb; if (c > 64) c = 64;
        int v = bedge[jb + (lane < c ? lane : c - 1)];
#pragma unroll
        for (int g0 = 0; g0 < 64; g0 += 8) {
            if (g0 >= c) break;
            int kidx = g0 + slot;
            int kc = kidx < c ? kidx : c - 1;
            int pk = __shfl(v, kc, 64);
            float a = hs2[(pk & 0x1FFFF) * 8 + chan];
            if (kidx < c) atomicAdd(&acc2[(pk >> 17) * 8 + chan], a);
        }
    }
    __syncthreads();

    for (int i = t; i < NPB * 8; i += 512) {
        int g8 = nbase * 8 + i;
        if (g8 < N_NODES * 8) agg2[g8] = acc2[i];
    }
}

// ---------------- final mean reduction ----------------
__global__ __launch_bounds__(256) void k_reduce1(const float* __restrict__ agg2,
                                                 const float* __restrict__ dinv,
                                                 float* __restrict__ partials) {
    float acc[NOUT] = {};
    for (int n = blockIdx.x * 256 + threadIdx.x; n < N_NODES; n += 256 * 1024) {
        float dv = dinv[n];
        const float* rp = agg2 + n * 8;
#pragma unroll
        for (int j = 0; j < NOUT; ++j) acc[j] += dv * rp[j];
    }
    __shared__ float s[NOUT * 256];
    for (int j = 0; j < NOUT; ++j) s[j * 256 + threadIdx.x] = acc[j];
    __syncthreads();
    for (int off = 128; off > 0; off >>= 1) {
        if (threadIdx.x < off)
            for (int j = 0; j < NOUT; ++j)
                s[j * 256 + threadIdx.x] += s[j * 256 + threadIdx.x + off];
        __syncthreads();
    }
    if (threadIdx.x == 0)
        for (int j = 0; j < NOUT; ++j) partials[blockIdx.x * 8 + j] = s[j * 256];
}

__global__ __launch_bounds__(256) void k_reduce2(const float* __restrict__ partials,
                                                 const float* __restrict__ b2,
                                                 float* __restrict__ out) {
    __shared__ float s[256];
    for (int j = 0; j < NOUT; ++j) {
        float a = 0.f;
        for (int p = threadIdx.x; p < 1024; p += 256) a += partials[p * 8 + j];
        s[threadIdx.x] = a;
        __syncthreads();
        for (int off = 128; off > 0; off >>= 1) {
            if (threadIdx.x < off) s[threadIdx.x] += s[threadIdx.x + off];
            __syncthreads();
        }
        if (threadIdx.x == 0) out[j] = b2[j] + s[0] * (1.0f / N_NODES);
        __syncthreads();
    }
}

extern "C" void kernel_launch(void* const* d_in, const int* in_sizes, int n_in,
                              void* d_out, int out_size, void* d_ws, size_t ws_size,
                              hipStream_t stream) {
    const float* x  = (const float*)d_in[0];
    const int*   ei = (const int*)d_in[1];
    const float* W1 = (const float*)d_in[2];
    const float* b1 = (const float*)d_in[3];
    const float* W2 = (const float*)d_in[4];
    const float* b2 = (const float*)d_in[5];
    float* out = (float*)d_out;

    float* fw       = (float*)d_ws;
    float* hs1      = fw;                          // N*64
    float* agg1     = hs1 + N_NODES * 64;          // N*64
    float* hs2      = agg1 + N_NODES * 64;         // N*8
    float* agg2     = hs2 + N_NODES * 8;           // N*8
    float* dinv     = agg2 + N_NODES * 8;          // N
    float* partials = dinv + N_NODES;              // 1024*8
    int* gcounts    = (int*)(partials + 1024 * 8); // 512
    int* bbase      = gcounts + 512;               // 512 (NBUK+1 used)
    int* gcursor    = bbase + 512;                 // 512
    int* bedge      = gcursor + 512;               // E

    const int* row = ei;              // sources
    const int* col = ei + N_EDGES;    // targets

    // build bucketed edge list
    k_zero512<<<1, 512, 0, stream>>>(gcounts);
    k_coarse_hist<<<1024, 256, 0, stream>>>(col, gcounts);
    k_coarse_scan<<<1, 512, 0, stream>>>(gcounts, bbase, gcursor);
    k_partition<<<PNB, 512, 0, stream>>>(row, col, gcursor, bedge);
    k_bucket_dinv<<<NBUK, 256, 0, stream>>>(bbase, bedge, dinv);

    // layer 1
    k_gemm1<<<(N_NODES + 63) / 64, 256, 0, stream>>>(x, W1, dinv, hs1);
    k_agg1b<<<NBUK, 512, 0, stream>>>(bbase, bedge, hs1, agg1);

    // layer 2
    k_layer2<<<(N_NODES + 127) / 128, 128, 0, stream>>>(agg1, W2, b1, dinv, hs2);
    k_agg2b<<<NBUK, 512, 0, stream>>>(bbase, bedge, hs2, agg2);

    // mean
    k_reduce1<<<1024, 256, 0, stream>>>(agg2, dinv, partials);
    k_reduce2<<<1, 256, 0, stream>>>(partials, b2, out);
}

// Round 4
// 397.231 us; speedup vs baseline: 4.2615x; 4.2615x over previous
//
#include <hip/hip_runtime.h>

#define N_NODES 100000
#define N_EDGES 3200000
#define NOUT 6

#define NPB 256                                   // nodes per bucket
#define NBUK ((N_NODES + NPB - 1) / NPB)          // 391
#define PCHUNK 4096                               // edges per partition block
#define PNB ((N_EDGES + PCHUNK - 1) / PCHUNK)     // 782
#define SORT_CAP 10240                            // LDS stage capacity (avg bucket ~8184)
#define NB2 ((N_NODES + 127) / 128)               // 782 layer2 blocks

// ---------------- zeros ----------------
__global__ __launch_bounds__(512) void k_zero512(int* __restrict__ p) {
    p[threadIdx.x] = 0;
}

__global__ __launch_bounds__(256) void k_zeroN(float* __restrict__ p, int n) {
    int i = blockIdx.x * 256 + threadIdx.x;
    if (i < n) p[i] = 0.f;
}

// ---------------- coarse histogram of target buckets ----------------
__global__ __launch_bounds__(256) void k_coarse_hist(const int* __restrict__ col,
                                                     int* __restrict__ gcounts) {
    __shared__ int h[512];
    const int t = threadIdx.x;
    for (int i = t; i < 512; i += 256) h[i] = 0;
    __syncthreads();
    for (int e = blockIdx.x * 256 + t; e < N_EDGES; e += 1024 * 256)
        atomicAdd(&h[col[e] >> 8], 1);
    __syncthreads();
    for (int i = t; i < 512; i += 256)
        if (h[i]) atomicAdd(&gcounts[i], h[i]);
}

// ---------------- scan bucket counts -> bbase, gcursor ----------------
__global__ __launch_bounds__(512) void k_coarse_scan(const int* __restrict__ gcounts,
                                                     int* __restrict__ bbase,
                                                     int* __restrict__ gcursor) {
    __shared__ int s[512];
    const int t = threadIdx.x;
    int v = (t < NBUK) ? gcounts[t] : 0;
    s[t] = v;
    __syncthreads();
    for (int off = 1; off < 512; off <<= 1) {
        int u = (t >= off) ? s[t - off] : 0;
        __syncthreads();
        s[t] += u;
        __syncthreads();
    }
    int excl = s[t] - v;
    if (t < NBUK) { bbase[t] = excl; gcursor[t] = excl; }
    if (t == 0) bbase[NBUK] = N_EDGES;
}

// ---------------- LDS-staged bucket partition: bedge[p] = (localcol<<17)|row ----------------
__global__ __launch_bounds__(512) void k_partition(const int* __restrict__ row,
                                                   const int* __restrict__ col,
                                                   int* __restrict__ gcursor,
                                                   int* __restrict__ bedge) {
    __shared__ int hist[512];
    __shared__ int lstart[512];
    __shared__ int lcur[512];
    __shared__ int gbase[512];
    __shared__ int sscan[512];
    __shared__ int stage[PCHUNK];
    __shared__ unsigned short stageb[PCHUNK];

    const int t = threadIdx.x;
    const int c0 = blockIdx.x * PCHUNK;
    int cnt = N_EDGES - c0; if (cnt > PCHUNK) cnt = PCHUNK;

    hist[t] = 0; lcur[t] = 0;
    __syncthreads();

    int myp[8]; int myb[8];
#pragma unroll
    for (int i = 0; i < 8; ++i) {
        int p = i * 512 + t;
        myb[i] = -1;
        if (p < cnt) {
            int e = c0 + p;
            int c = col[e], r = row[e];
            int b = c >> 8;
            myp[i] = ((c & 255) << 17) | r;
            myb[i] = b;
            atomicAdd(&hist[b], 1);
        }
    }
    __syncthreads();

    int hv = hist[t];
    sscan[t] = hv;
    __syncthreads();
    for (int off = 1; off < 512; off <<= 1) {
        int u = (t >= off) ? sscan[t - off] : 0;
        __syncthreads();
        sscan[t] += u;
        __syncthreads();
    }
    lstart[t] = sscan[t] - hv;
    if (t < NBUK && hv > 0) gbase[t] = atomicAdd(&gcursor[t], hv);
    __syncthreads();

#pragma unroll
    for (int i = 0; i < 8; ++i) {
        if (myb[i] >= 0) {
            int pos = lstart[myb[i]] + atomicAdd(&lcur[myb[i]], 1);
            stage[pos] = myp[i];
            stageb[pos] = (unsigned short)myb[i];
        }
    }
    __syncthreads();

    for (int p = t; p < cnt; p += 512) {
        int b = stageb[p];
        bedge[gbase[b] + p - lstart[b]] = stage[p];
    }
}

// ---------------- per-bucket counting sort -> sorted_row + node offsets + dinv + W ----------------
__global__ __launch_bounds__(256) void k_bucket_sort(const int* __restrict__ bbase,
                                                     const int* __restrict__ bedge,
                                                     float* __restrict__ dinv,
                                                     int* __restrict__ node_off,
                                                     int* __restrict__ sorted_row,
                                                     float* __restrict__ Wt) {
    __shared__ int cnt[NPB];
    __shared__ int lstart[NPB];
    __shared__ int lcur[NPB];
    __shared__ int sc[NPB];
    __shared__ float fdinv[NPB];
    __shared__ int stage[SORT_CAP];

    const int t = threadIdx.x;
    const int b = blockIdx.x;
    const int s = bbase[b], e = bbase[b + 1], m = e - s;

    cnt[t] = 0; lcur[t] = 0;
    __syncthreads();
    for (int j = s + t; j < e; j += 256) atomicAdd(&cnt[bedge[j] >> 17], 1);
    __syncthreads();

    int c = cnt[t];
    sc[t] = c;
    __syncthreads();
    for (int off = 1; off < 256; off <<= 1) {
        int u = (t >= off) ? sc[t - off] : 0;
        __syncthreads();
        sc[t] += u;
        __syncthreads();
    }
    lstart[t] = sc[t] - c;
    int g = b * NPB + t;
    node_off[g] = s + sc[t] - c;                 // padding nodes get s+m -> correct sentinels
    float dv = rsqrtf((float)c + 1.0f);          // +1 self-loop
    fdinv[t] = dv;
    if (g < N_NODES) dinv[g] = dv;
    __syncthreads();

    if (m <= SORT_CAP) {
        for (int j = s + t; j < e; j += 256) {
            int p = bedge[j]; int lc = p >> 17;
            int pos = lstart[lc] + atomicAdd(&lcur[lc], 1);
            stage[pos] = p;
        }
        __syncthreads();
        for (int j = t; j < m; j += 256) {       // coalesced write + W accumulation
            int p = stage[j];
            sorted_row[s + j] = p & 0x1FFFF;
            unsafeAtomicAdd(&Wt[p & 0x1FFFF], fdinv[p >> 17]);
        }
    } else {                                      // safe fallback (never for this input)
        for (int j = s + t; j < e; j += 256) {
            int p = bedge[j]; int lc = p >> 17;
            int pos = lstart[lc] + atomicAdd(&lcur[lc], 1);
            sorted_row[s + pos] = p & 0x1FFFF;
            unsafeAtomicAdd(&Wt[p & 0x1FFFF], fdinv[lc]);
        }
    }
}

// ---------------- layer 1 GEMM: hs1 = (x @ W1) * dinv ----------------
__global__ __launch_bounds__(256) void k_gemm1(const float* __restrict__ x,
                                               const float* __restrict__ W1,
                                               const float* __restrict__ dinv,
                                               float* __restrict__ hs1) {
    __shared__ float Ws[64 * 64];
    __shared__ float Xs[64 * 65];
    const int tx = threadIdx.x;
    const int nodeBase = blockIdx.x * 64;

    for (int t = tx; t < 64 * 64; t += 256) Ws[t] = W1[t];

    for (int t = tx; t < 64 * 16; t += 256) {
        int r = t >> 4, c4 = t & 15;
        int g = nodeBase + r;
        float4 v = make_float4(0.f, 0.f, 0.f, 0.f);
        if (g < N_NODES) v = reinterpret_cast<const float4*>(x)[g * 16 + c4];
        float* p = &Xs[r * 65 + c4 * 4];
        p[0] = v.x; p[1] = v.y; p[2] = v.z; p[3] = v.w;
    }
    __syncthreads();

    const int nG = tx >> 4;
    const int cG = tx & 15;
    float acc[4][4] = {};
    for (int k = 0; k < 64; ++k) {
        float4 w = *reinterpret_cast<const float4*>(&Ws[k * 64 + cG * 4]);
#pragma unroll
        for (int i = 0; i < 4; ++i) {
            float xv = Xs[(nG * 4 + i) * 65 + k];
            acc[i][0] = fmaf(xv, w.x, acc[i][0]);
            acc[i][1] = fmaf(xv, w.y, acc[i][1]);
            acc[i][2] = fmaf(xv, w.z, acc[i][2]);
            acc[i][3] = fmaf(xv, w.w, acc[i][3]);
        }
    }

#pragma unroll
    for (int i = 0; i < 4; ++i) {
        int n = nodeBase + nG * 4 + i;
        if (n < N_NODES) {
            float dv = dinv[n];
            float4 o = make_float4(acc[i][0] * dv, acc[i][1] * dv, acc[i][2] * dv, acc[i][3] * dv);
            reinterpret_cast<float4*>(hs1)[n * 16 + cG] = o;
        }
    }
}

// ---------------- segment-sum layer 1: wave per node, lane = channel ----------------
__global__ __launch_bounds__(256) void k_agg1(const int* __restrict__ node_off,
                                              const int* __restrict__ sorted_row,
                                              const float* __restrict__ hs1,
                                              float* __restrict__ agg1) {
    int wid = (blockIdx.x * 256 + threadIdx.x) >> 6;
    int lane = threadIdx.x & 63;
    if (wid >= N_NODES) return;
    int s = node_off[wid], e = node_off[wid + 1];
    float acc = hs1[wid * 64 + lane];                  // self-loop term
    int j = s;
    for (; j + 4 <= e; j += 4) {                       // 4 independent gathers in flight
        int r0 = sorted_row[j], r1 = sorted_row[j + 1];
        int r2 = sorted_row[j + 2], r3 = sorted_row[j + 3];
        float a = hs1[r0 * 64 + lane];
        float b = hs1[r1 * 64 + lane];
        float c = hs1[r2 * 64 + lane];
        float d = hs1[r3 * 64 + lane];
        acc += (a + b) + (c + d);
    }
    for (; j < e; ++j) acc += hs1[sorted_row[j] * 64 + lane];
    agg1[wid * 64 + lane] = acc;
}

// ---- layer 2 fused: h1=relu(dinv*agg1+b1); hs2=(h1@W2)*dinv; partial += (dinv+W)*hs2 ----
__global__ __launch_bounds__(128) void k_layer2f(const float* __restrict__ agg1,
                                                 const float* __restrict__ W2,
                                                 const float* __restrict__ b1,
                                                 const float* __restrict__ dinv,
                                                 const float* __restrict__ Wt,
                                                 float* __restrict__ partials) {
    __shared__ float W2s[64][8];
    __shared__ float b1s[64];
    __shared__ float Xs[128][65];
    __shared__ float wred[2][8];
    const int tx = threadIdx.x;
    if (tx < 64) b1s[tx] = b1[tx];
    for (int t = tx; t < 64 * NOUT; t += 128) W2s[t / NOUT][t % NOUT] = W2[t];

    const int nodeBase = blockIdx.x * 128;
    for (int t = tx; t < 128 * 16; t += 128) {
        int r = t >> 4, c4 = t & 15;
        int g = nodeBase + r;
        float4 v = make_float4(0.f, 0.f, 0.f, 0.f);
        if (g < N_NODES) v = reinterpret_cast<const float4*>(agg1)[g * 16 + c4];
        float* p = &Xs[r][c4 * 4];
        p[0] = v.x; p[1] = v.y; p[2] = v.z; p[3] = v.w;
    }
    __syncthreads();

    int n = nodeBase + tx;
    float dv = 0.f, wv = 0.f;
    if (n < N_NODES) { dv = dinv[n]; wv = Wt[n]; }
    float acc[NOUT] = {};
    for (int k = 0; k < 64; ++k) {
        float hv = fmaxf(fmaf(dv, Xs[tx][k], b1s[k]), 0.f);
#pragma unroll
        for (int j = 0; j < NOUT; ++j) acc[j] = fmaf(hv, W2s[k][j], acc[j]);
    }
    float scale = dv * (dv + wv);                // 0 for OOB nodes (dv=0)

    const int lane = tx & 63, w = tx >> 6;
#pragma unroll
    for (int j = 0; j < NOUT; ++j) {
        float v = acc[j] * scale;
        v += __shfl_xor(v, 1, 64);
        v += __shfl_xor(v, 2, 64);
        v += __shfl_xor(v, 4, 64);
        v += __shfl_xor(v, 8, 64);
        v += __shfl_xor(v, 16, 64);
        v += __shfl_xor(v, 32, 64);
        if (lane == 0) wred[w][j] = v;
    }
    __syncthreads();
    if (tx < NOUT) partials[blockIdx.x * 8 + tx] = wred[0][tx] + wred[1][tx];
}

// ---------------- final reduction over block partials ----------------
__global__ __launch_bounds__(256) void k_reduce2(const float* __restrict__ partials,
                                                 const float* __restrict__ b2,
                                                 float* __restrict__ out) {
    __shared__ float s[256];
    for (int j = 0; j < NOUT; ++j) {
        float a = 0.f;
        for (int p = threadIdx.x; p < NB2; p += 256) a += partials[p * 8 + j];
        s[threadIdx.x] = a;
        __syncthreads();
        for (int off = 128; off > 0; off >>= 1) {
            if (threadIdx.x < off) s[threadIdx.x] += s[threadIdx.x + off];
            __syncthreads();
        }
        if (threadIdx.x == 0) out[j] = b2[j] + s[0] * (1.0f / N_NODES);
        __syncthreads();
    }
}

extern "C" void kernel_launch(void* const* d_in, const int* in_sizes, int n_in,
                              void* d_out, int out_size, void* d_ws, size_t ws_size,
                              hipStream_t stream) {
    const float* x  = (const float*)d_in[0];
    const int*   ei = (const int*)d_in[1];
    const float* W1 = (const float*)d_in[2];
    const float* b1 = (const float*)d_in[3];
    const float* W2 = (const float*)d_in[4];
    const float* b2 = (const float*)d_in[5];
    float* out = (float*)d_out;

    // layout (words); agg1 aliases bedge (bedge dead after k_bucket_sort)
    float* hs1       = (float*)d_ws;                    // 6,400,000
    float* dinv      = hs1 + 6400000;                   // 100,352
    float* Wt        = dinv + 100352;                   // 100,352
    float* partials  = Wt + 100352;                     // 8,192
    int*   gcounts   = (int*)(partials + 8192);         // 512
    int*   bbase     = gcounts + 512;                   // 512
    int*   gcursor   = bbase + 512;                     // 512
    int*   node_off  = gcursor + 512;                   // 100,160 (NBUK*NPB + pad)
    int*   sorted_row= node_off + 100160;               // 3,200,000
    int*   bedge     = sorted_row + 3200000;            // 3,200,000
    float* agg1      = (float*)bedge;                   // 6,400,000 (reuses bedge + beyond)

    const int* row = ei;              // sources
    const int* col = ei + N_EDGES;    // targets

    // build bucketed, then per-node-sorted edge list; dinv; W
    k_zero512<<<1, 512, 0, stream>>>(gcounts);
    k_zeroN<<<(N_NODES + 255) / 256, 256, 0, stream>>>(Wt, N_NODES);
    k_coarse_hist<<<1024, 256, 0, stream>>>(col, gcounts);
    k_coarse_scan<<<1, 512, 0, stream>>>(gcounts, bbase, gcursor);
    k_partition<<<PNB, 512, 0, stream>>>(row, col, gcursor, bedge);
    k_bucket_sort<<<NBUK, 256, 0, stream>>>(bbase, bedge, dinv, node_off, sorted_row, Wt);

    // layer 1
    k_gemm1<<<(N_NODES + 63) / 64, 256, 0, stream>>>(x, W1, dinv, hs1);
    k_agg1<<<(N_NODES * 64 + 255) / 256, 256, 0, stream>>>(node_off, sorted_row, hs1, agg1);

    // layer 2 (aggregation algebraically folded into the mean via W)
    k_layer2f<<<NB2, 128, 0, stream>>>(agg1, W2, b1, dinv, Wt, partials);
    k_reduce2<<<1, 256, 0, stream>>>(partials, b2, out);
}

// Round 5
// 274.432 us; speedup vs baseline: 6.1684x; 1.4475x over previous
//
#include <hip/hip_runtime.h>

#define N_NODES 100000
#define N_EDGES 3200000
#define NOUT 6

#define NPB 256                                   // nodes per bucket
#define NBUK ((N_NODES + NPB - 1) / NPB)          // 391
#define PCHUNK 4096                               // edges per partition block
#define PNB ((N_EDGES + PCHUNK - 1) / PCHUNK)     // 782
#define SORT_CAP 10240                            // LDS stage capacity (avg bucket ~8184, 22 sigma)
#define NB2 ((N_NODES + 127) / 128)               // 782 layer2 blocks
#define WSB 1024                                  // k_wsum blocks
#define NPART (NB2 + WSB)                         // total partial groups

// ---------------- zeros ----------------
__global__ __launch_bounds__(512) void k_zero512(int* __restrict__ p) {
    p[threadIdx.x] = 0;
}

// ---------------- coarse histogram of target buckets ----------------
__global__ __launch_bounds__(256) void k_coarse_hist(const int* __restrict__ col,
                                                     int* __restrict__ gcounts) {
    __shared__ int h[512];
    const int t = threadIdx.x;
    for (int i = t; i < 512; i += 256) h[i] = 0;
    __syncthreads();
    for (int e = blockIdx.x * 256 + t; e < N_EDGES; e += 1024 * 256)
        atomicAdd(&h[col[e] >> 8], 1);
    __syncthreads();
    for (int i = t; i < 512; i += 256)
        if (h[i]) atomicAdd(&gcounts[i], h[i]);
}

// ---------------- scan bucket counts -> bbase, gcursor ----------------
__global__ __launch_bounds__(512) void k_coarse_scan(const int* __restrict__ gcounts,
                                                     int* __restrict__ bbase,
                                                     int* __restrict__ gcursor) {
    __shared__ int s[512];
    const int t = threadIdx.x;
    int v = (t < NBUK) ? gcounts[t] : 0;
    s[t] = v;
    __syncthreads();
    for (int off = 1; off < 512; off <<= 1) {
        int u = (t >= off) ? s[t - off] : 0;
        __syncthreads();
        s[t] += u;
        __syncthreads();
    }
    int excl = s[t] - v;
    if (t < NBUK) { bbase[t] = excl; gcursor[t] = excl; }
    if (t == 0) bbase[NBUK] = N_EDGES;
}

// ---------------- LDS-staged bucket partition: bedge[p] = (localcol<<17)|row ----------------
__global__ __launch_bounds__(512) void k_partition(const int* __restrict__ row,
                                                   const int* __restrict__ col,
                                                   int* __restrict__ gcursor,
                                                   int* __restrict__ bedge) {
    __shared__ int hist[512];
    __shared__ int lstart[512];
    __shared__ int lcur[512];
    __shared__ int gbase[512];
    __shared__ int sscan[512];
    __shared__ int stage[PCHUNK];
    __shared__ unsigned short stageb[PCHUNK];

    const int t = threadIdx.x;
    const int c0 = blockIdx.x * PCHUNK;
    int cnt = N_EDGES - c0; if (cnt > PCHUNK) cnt = PCHUNK;

    hist[t] = 0; lcur[t] = 0;
    __syncthreads();

    int myp[8]; int myb[8];
#pragma unroll
    for (int i = 0; i < 8; ++i) {
        int p = i * 512 + t;
        myb[i] = -1;
        if (p < cnt) {
            int e = c0 + p;
            int c = col[e], r = row[e];
            int b = c >> 8;
            myp[i] = ((c & 255) << 17) | r;
            myb[i] = b;
            atomicAdd(&hist[b], 1);
        }
    }
    __syncthreads();

    int hv = hist[t];
    sscan[t] = hv;
    __syncthreads();
    for (int off = 1; off < 512; off <<= 1) {
        int u = (t >= off) ? sscan[t - off] : 0;
        __syncthreads();
        sscan[t] += u;
        __syncthreads();
    }
    lstart[t] = sscan[t] - hv;
    if (t < NBUK && hv > 0) gbase[t] = atomicAdd(&gcursor[t], hv);
    __syncthreads();

#pragma unroll
    for (int i = 0; i < 8; ++i) {
        if (myb[i] >= 0) {
            int pos = lstart[myb[i]] + atomicAdd(&lcur[myb[i]], 1);
            stage[pos] = myp[i];
            stageb[pos] = (unsigned short)myb[i];
        }
    }
    __syncthreads();

    for (int p = t; p < cnt; p += 512) {
        int b = stageb[p];
        bedge[gbase[b] + p - lstart[b]] = stage[p];
    }
}

// ---- per-bucket counting sort (single LDS pass) -> sorted_row + node offsets + dinv ----
__global__ __launch_bounds__(512) void k_bucket_sort(const int* __restrict__ bbase,
                                                     const int* __restrict__ bedge,
                                                     float* __restrict__ dinv,
                                                     int* __restrict__ node_off,
                                                     int* __restrict__ sorted_row) {
    __shared__ int cnt[NPB];
    __shared__ int lstart[NPB];
    __shared__ int lcur[NPB];
    __shared__ int sc[NPB];
    __shared__ int stage[SORT_CAP];

    const int t = threadIdx.x;
    const int b = blockIdx.x;
    const int s = bbase[b], e = bbase[b + 1], m = e - s;
    const bool fits = (m <= SORT_CAP);

    if (t < NPB) { cnt[t] = 0; lcur[t] = 0; }
    __syncthreads();

    if (fits) {
        for (int j = t; j < m; j += 512) {          // single coalesced global read
            int p = bedge[s + j];
            stage[j] = p;
            atomicAdd(&cnt[p >> 17], 1);
        }
    } else {
        for (int j = t; j < m; j += 512) atomicAdd(&cnt[bedge[s + j] >> 17], 1);
    }
    __syncthreads();

    if (t < NPB) sc[t] = cnt[t];
    __syncthreads();
    for (int off = 1; off < NPB; off <<= 1) {
        int u = 0;
        if (t < NPB && t >= off) u = sc[t - off];
        __syncthreads();
        if (t < NPB && t >= off) sc[t] += u;
        __syncthreads();
    }
    if (t < NPB) {
        int c = cnt[t];
        lstart[t] = sc[t] - c;
        int g = b * NPB + t;
        node_off[g] = s + sc[t] - c;                // padding nodes -> sentinel s+m
        if (g < N_NODES) dinv[g] = rsqrtf((float)c + 1.0f);   // +1 self-loop
    }
    __syncthreads();

    if (fits) {
        for (int j = t; j < m; j += 512) {          // scatter into compact L2-resident window
            int p = stage[j];
            int lc = p >> 17;
            int pos = lstart[lc] + atomicAdd(&lcur[lc], 1);
            sorted_row[s + pos] = p & 0x1FFFF;
        }
    } else {
        for (int j = t; j < m; j += 512) {
            int p = bedge[s + j];
            int lc = p >> 17;
            int pos = lstart[lc] + atomicAdd(&lcur[lc], 1);
            sorted_row[s + pos] = p & 0x1FFFF;
        }
    }
}

// ---------------- layer 1 GEMM: hs1 = (x @ W1) * dinv ----------------
__global__ __launch_bounds__(256) void k_gemm1(const float* __restrict__ x,
                                               const float* __restrict__ W1,
                                               const float* __restrict__ dinv,
                                               float* __restrict__ hs1) {
    __shared__ float Ws[64 * 64];
    __shared__ float Xs[64 * 65];
    const int tx = threadIdx.x;
    const int nodeBase = blockIdx.x * 64;

    for (int t = tx; t < 64 * 64; t += 256) Ws[t] = W1[t];

    for (int t = tx; t < 64 * 16; t += 256) {
        int r = t >> 4, c4 = t & 15;
        int g = nodeBase + r;
        float4 v = make_float4(0.f, 0.f, 0.f, 0.f);
        if (g < N_NODES) v = reinterpret_cast<const float4*>(x)[g * 16 + c4];
        float* p = &Xs[r * 65 + c4 * 4];
        p[0] = v.x; p[1] = v.y; p[2] = v.z; p[3] = v.w;
    }
    __syncthreads();

    const int nG = tx >> 4;
    const int cG = tx & 15;
    float acc[4][4] = {};
    for (int k = 0; k < 64; ++k) {
        float4 w = *reinterpret_cast<const float4*>(&Ws[k * 64 + cG * 4]);
#pragma unroll
        for (int i = 0; i < 4; ++i) {
            float xv = Xs[(nG * 4 + i) * 65 + k];
            acc[i][0] = fmaf(xv, w.x, acc[i][0]);
            acc[i][1] = fmaf(xv, w.y, acc[i][1]);
            acc[i][2] = fmaf(xv, w.z, acc[i][2]);
            acc[i][3] = fmaf(xv, w.w, acc[i][3]);
        }
    }

#pragma unroll
    for (int i = 0; i < 4; ++i) {
        int n = nodeBase + nG * 4 + i;
        if (n < N_NODES) {
            float dv = dinv[n];
            float4 o = make_float4(acc[i][0] * dv, acc[i][1] * dv, acc[i][2] * dv, acc[i][3] * dv);
            reinterpret_cast<float4*>(hs1)[n * 16 + cG] = o;
        }
    }
}

// ---------------- segment-sum layer 1: 16 lanes/node, lane = float4 channel group ----------------
__global__ __launch_bounds__(256) void k_agg1(const int* __restrict__ node_off,
                                              const int* __restrict__ sorted_row,
                                              const float* __restrict__ hs1,
                                              float* __restrict__ agg1) {
    int tid = blockIdx.x * 256 + threadIdx.x;
    int node = tid >> 4;
    int l16 = tid & 15;
    if (node >= N_NODES) return;
    int s = node_off[node], e = node_off[node + 1];
    const float4* h4 = reinterpret_cast<const float4*>(hs1);
    float4 acc = h4[node * 16 + l16];                  // self-loop term
    int j = s;
    for (; j + 4 <= e; j += 4) {                       // 4 independent 16B gathers in flight
        int r0 = sorted_row[j],     r1 = sorted_row[j + 1];
        int r2 = sorted_row[j + 2], r3 = sorted_row[j + 3];
        float4 a = h4[r0 * 16 + l16];
        float4 b = h4[r1 * 16 + l16];
        float4 c = h4[r2 * 16 + l16];
        float4 d = h4[r3 * 16 + l16];
        acc.x += (a.x + b.x) + (c.x + d.x);
        acc.y += (a.y + b.y) + (c.y + d.y);
        acc.z += (a.z + b.z) + (c.z + d.z);
        acc.w += (a.w + b.w) + (c.w + d.w);
    }
    for (; j < e; ++j) {
        float4 a = h4[sorted_row[j] * 16 + l16];
        acc.x += a.x; acc.y += a.y; acc.z += a.z; acc.w += a.w;
    }
    reinterpret_cast<float4*>(agg1)[node * 16 + l16] = acc;
}

// ---- layer 2 fused: h1=relu(dinv*agg1+b1); hs2=(h1@W2)*dinv (stored); partial += dinv*hs2 ----
__global__ __launch_bounds__(128) void k_layer2f(const float* __restrict__ agg1,
                                                 const float* __restrict__ W2,
                                                 const float* __restrict__ b1,
                                                 const float* __restrict__ dinv,
                                                 float* __restrict__ hs2,
                                                 float* __restrict__ partials) {
    __shared__ float W2s[64][8];
    __shared__ float b1s[64];
    __shared__ float Xs[128][65];
    __shared__ float wred[2][8];
    const int tx = threadIdx.x;
    if (tx < 64) b1s[tx] = b1[tx];
    for (int t = tx; t < 64 * NOUT; t += 128) W2s[t / NOUT][t % NOUT] = W2[t];

    const int nodeBase = blockIdx.x * 128;
    for (int t = tx; t < 128 * 16; t += 128) {
        int r = t >> 4, c4 = t & 15;
        int g = nodeBase + r;
        float4 v = make_float4(0.f, 0.f, 0.f, 0.f);
        if (g < N_NODES) v = reinterpret_cast<const float4*>(agg1)[g * 16 + c4];
        float* p = &Xs[r][c4 * 4];
        p[0] = v.x; p[1] = v.y; p[2] = v.z; p[3] = v.w;
    }
    __syncthreads();

    int n = nodeBase + tx;
    float dv = (n < N_NODES) ? dinv[n] : 0.f;
    float acc[NOUT] = {};
    for (int k = 0; k < 64; ++k) {
        float hv = fmaxf(fmaf(dv, Xs[tx][k], b1s[k]), 0.f);
#pragma unroll
        for (int j = 0; j < NOUT; ++j) acc[j] = fmaf(hv, W2s[k][j], acc[j]);
    }
    if (n < N_NODES) {                               // hs2 = acc * dinv
        float4 o0 = make_float4(acc[0] * dv, acc[1] * dv, acc[2] * dv, acc[3] * dv);
        reinterpret_cast<float4*>(hs2)[n * 2] = o0;
        float2 o1 = make_float2(acc[4] * dv, acc[5] * dv);
        reinterpret_cast<float2*>(hs2)[n * 4 + 2] = o1;
    }
    float scale = dv * dv;                           // self term: dinv * hs2 = dinv^2 * acc

    const int lane = tx & 63, w = tx >> 6;
#pragma unroll
    for (int j = 0; j < NOUT; ++j) {
        float v = acc[j] * scale;
        v += __shfl_xor(v, 1, 64);
        v += __shfl_xor(v, 2, 64);
        v += __shfl_xor(v, 4, 64);
        v += __shfl_xor(v, 8, 64);
        v += __shfl_xor(v, 16, 64);
        v += __shfl_xor(v, 32, 64);
        if (lane == 0) wred[w][j] = v;
    }
    __syncthreads();
    if (tx < NOUT) partials[blockIdx.x * 8 + tx] = wred[0][tx] + wred[1][tx];
}

// ---- edge-stream W-term: partial += dinv[col] * hs2[row], zero atomics ----
__global__ __launch_bounds__(256) void k_wsum(const int* __restrict__ row,
                                              const int* __restrict__ col,
                                              const float* __restrict__ dinv,
                                              const float* __restrict__ hs2,
                                              float* __restrict__ partials) {
    float a0 = 0.f, a1 = 0.f, a2 = 0.f, a3 = 0.f, a4 = 0.f, a5 = 0.f;
    for (int e = blockIdx.x * 256 + threadIdx.x; e < N_EDGES; e += WSB * 256) {
        int r = row[e], c = col[e];
        float dv = dinv[c];
        float4 h0 = reinterpret_cast<const float4*>(hs2)[r * 2];
        float2 h1 = reinterpret_cast<const float2*>(hs2)[r * 4 + 2];
        a0 = fmaf(dv, h0.x, a0);
        a1 = fmaf(dv, h0.y, a1);
        a2 = fmaf(dv, h0.z, a2);
        a3 = fmaf(dv, h0.w, a3);
        a4 = fmaf(dv, h1.x, a4);
        a5 = fmaf(dv, h1.y, a5);
    }
    __shared__ float wred[4][8];
    const int tx = threadIdx.x, lane = tx & 63, w = tx >> 6;
    float v[NOUT] = {a0, a1, a2, a3, a4, a5};
#pragma unroll
    for (int j = 0; j < NOUT; ++j) {
        float u = v[j];
        u += __shfl_xor(u, 1, 64);
        u += __shfl_xor(u, 2, 64);
        u += __shfl_xor(u, 4, 64);
        u += __shfl_xor(u, 8, 64);
        u += __shfl_xor(u, 16, 64);
        u += __shfl_xor(u, 32, 64);
        if (lane == 0) wred[w][j] = u;
    }
    __syncthreads();
    if (tx < NOUT)
        partials[(NB2 + blockIdx.x) * 8 + tx] = wred[0][tx] + wred[1][tx] + wred[2][tx] + wred[3][tx];
}

// ---------------- final reduction over all partial groups ----------------
__global__ __launch_bounds__(256) void k_reduce2(const float* __restrict__ partials,
                                                 const float* __restrict__ b2,
                                                 float* __restrict__ out) {
    __shared__ float s[256];
    for (int j = 0; j < NOUT; ++j) {
        float a = 0.f;
        for (int p = threadIdx.x; p < NPART; p += 256) a += partials[p * 8 + j];
        s[threadIdx.x] = a;
        __syncthreads();
        for (int off = 128; off > 0; off >>= 1) {
            if (threadIdx.x < off) s[threadIdx.x] += s[threadIdx.x + off];
            __syncthreads();
        }
        if (threadIdx.x == 0) out[j] = b2[j] + s[0] * (1.0f / N_NODES);
        __syncthreads();
    }
}

extern "C" void kernel_launch(void* const* d_in, const int* in_sizes, int n_in,
                              void* d_out, int out_size, void* d_ws, size_t ws_size,
                              hipStream_t stream) {
    const float* x  = (const float*)d_in[0];
    const int*   ei = (const int*)d_in[1];
    const float* W1 = (const float*)d_in[2];
    const float* b1 = (const float*)d_in[3];
    const float* W2 = (const float*)d_in[4];
    const float* b2 = (const float*)d_in[5];
    float* out = (float*)d_out;

    // layout (words, all 16B-aligned):
    // agg1 aliases bedge (dead after k_bucket_sort); hs2 aliases sorted_row (dead after k_agg1)
    float* hs1       = (float*)d_ws;                    // 6,400,000
    float* dinv      = hs1 + 6400000;                   // 100,352
    float* partials  = dinv + 100352;                   // 16,384 (NPART*8 = 14,448 used)
    int*   gcounts   = (int*)(partials + 16384);        // 512
    int*   bbase     = gcounts + 512;                   // 512
    int*   gcursor   = bbase + 512;                     // 512
    int*   node_off  = gcursor + 512;                   // 100,160 (NBUK*NPB+pad)
    int*   sorted_row= node_off + 100160;               // 3,200,000
    int*   bedge     = sorted_row + 3200000;            // 3,200,000
    float* agg1      = (float*)bedge;                   // 6,400,000 (reuses bedge + beyond)
    float* hs2       = (float*)sorted_row;              // 802,816 (reuses sorted_row)

    const int* row = ei;              // sources
    const int* col = ei + N_EDGES;    // targets

    // build bucketed, then per-node-sorted edge list; dinv
    k_zero512<<<1, 512, 0, stream>>>(gcounts);
    k_coarse_hist<<<1024, 256, 0, stream>>>(col, gcounts);
    k_coarse_scan<<<1, 512, 0, stream>>>(gcounts, bbase, gcursor);
    k_partition<<<PNB, 512, 0, stream>>>(row, col, gcursor, bedge);
    k_bucket_sort<<<NBUK, 512, 0, stream>>>(bbase, bedge, dinv, node_off, sorted_row);

    // layer 1
    k_gemm1<<<(N_NODES + 63) / 64, 256, 0, stream>>>(x, W1, dinv, hs1);
    k_agg1<<<(N_NODES * 16 + 255) / 256, 256, 0, stream>>>(node_off, sorted_row, hs1, agg1);

    // layer 2: GEMM fused with self-term partials; then edge-stream W-term
    k_layer2f<<<NB2, 128, 0, stream>>>(agg1, W2, b1, dinv, hs2, partials);
    k_wsum<<<WSB, 256, 0, stream>>>(row, col, dinv, hs2, partials);

    k_reduce2<<<1, 256, 0, stream>>>(partials, b2, out);
}

// Round 6
// 219.668 us; speedup vs baseline: 7.7062x; 1.2493x over previous
//
#include <hip/hip_runtime.h>

#define N_NODES 100000
#define N_EDGES 3200000
#define NOUT 6

#define NPB 256                                   // nodes per bucket
#define NBUK ((N_NODES + NPB - 1) / NPB)          // 391
#define PCHUNK 4096                               // edges per partition block
#define PNB ((N_EDGES + PCHUNK - 1) / PCHUNK)     // 782
#define SORT_CAP 10240                            // LDS stage capacity (avg bucket ~8184)
#define AGB (N_NODES / 32)                        // 3125 fused agg+layer2 blocks (32 nodes/block)
#define WSB 1024                                  // k_wsum blocks
#define NPART (AGB + WSB)                         // total partial groups

// ---------------- zeros ----------------
__global__ __launch_bounds__(512) void k_zero512(int* __restrict__ p) {
    p[threadIdx.x] = 0;
}

// ---------------- coarse histogram of target buckets ----------------
__global__ __launch_bounds__(256) void k_coarse_hist(const int* __restrict__ col,
                                                     int* __restrict__ gcounts) {
    __shared__ int h[512];
    const int t = threadIdx.x;
    for (int i = t; i < 512; i += 256) h[i] = 0;
    __syncthreads();
    for (int e = blockIdx.x * 256 + t; e < N_EDGES; e += 1024 * 256)
        atomicAdd(&h[col[e] >> 8], 1);
    __syncthreads();
    for (int i = t; i < 512; i += 256)
        if (h[i]) atomicAdd(&gcounts[i], h[i]);
}

// ---------------- scan bucket counts -> bbase, gcursor ----------------
__global__ __launch_bounds__(512) void k_coarse_scan(const int* __restrict__ gcounts,
                                                     int* __restrict__ bbase,
                                                     int* __restrict__ gcursor) {
    __shared__ int s[512];
    const int t = threadIdx.x;
    int v = (t < NBUK) ? gcounts[t] : 0;
    s[t] = v;
    __syncthreads();
    for (int off = 1; off < 512; off <<= 1) {
        int u = (t >= off) ? s[t - off] : 0;
        __syncthreads();
        s[t] += u;
        __syncthreads();
    }
    int excl = s[t] - v;
    if (t < NBUK) { bbase[t] = excl; gcursor[t] = excl; }
    if (t == 0) bbase[NBUK] = N_EDGES;
}

// ---------------- LDS-staged bucket partition: bedge[p] = (localcol<<17)|row ----------------
__global__ __launch_bounds__(512) void k_partition(const int* __restrict__ row,
                                                   const int* __restrict__ col,
                                                   int* __restrict__ gcursor,
                                                   int* __restrict__ bedge) {
    __shared__ int hist[512];
    __shared__ int lstart[512];
    __shared__ int lcur[512];
    __shared__ int gbase[512];
    __shared__ int sscan[512];
    __shared__ int stage[PCHUNK];
    __shared__ unsigned short stageb[PCHUNK];

    const int t = threadIdx.x;
    const int c0 = blockIdx.x * PCHUNK;
    int cnt = N_EDGES - c0; if (cnt > PCHUNK) cnt = PCHUNK;

    hist[t] = 0; lcur[t] = 0;
    __syncthreads();

    int myp[8]; int myb[8];
#pragma unroll
    for (int i = 0; i < 8; ++i) {
        int p = i * 512 + t;
        myb[i] = -1;
        if (p < cnt) {
            int e = c0 + p;
            int c = col[e], r = row[e];
            int b = c >> 8;
            myp[i] = ((c & 255) << 17) | r;
            myb[i] = b;
            atomicAdd(&hist[b], 1);
        }
    }
    __syncthreads();

    int hv = hist[t];
    sscan[t] = hv;
    __syncthreads();
    for (int off = 1; off < 512; off <<= 1) {
        int u = (t >= off) ? sscan[t - off] : 0;
        __syncthreads();
        sscan[t] += u;
        __syncthreads();
    }
    lstart[t] = sscan[t] - hv;
    if (t < NBUK && hv > 0) gbase[t] = atomicAdd(&gcursor[t], hv);
    __syncthreads();

#pragma unroll
    for (int i = 0; i < 8; ++i) {
        if (myb[i] >= 0) {
            int pos = lstart[myb[i]] + atomicAdd(&lcur[myb[i]], 1);
            stage[pos] = myp[i];
            stageb[pos] = (unsigned short)myb[i];
        }
    }
    __syncthreads();

    for (int p = t; p < cnt; p += 512) {
        int b = stageb[p];
        bedge[gbase[b] + p - lstart[b]] = stage[p];
    }
}

// ---- per-bucket counting sort (single LDS pass) -> sorted_row + node offsets + dinv ----
__global__ __launch_bounds__(512) void k_bucket_sort(const int* __restrict__ bbase,
                                                     const int* __restrict__ bedge,
                                                     float* __restrict__ dinv,
                                                     int* __restrict__ node_off,
                                                     int* __restrict__ sorted_row) {
    __shared__ int cnt[NPB];
    __shared__ int lstart[NPB];
    __shared__ int lcur[NPB];
    __shared__ int sc[NPB];
    __shared__ int stage[SORT_CAP];

    const int t = threadIdx.x;
    const int b = blockIdx.x;
    const int s = bbase[b], e = bbase[b + 1], m = e - s;
    const bool fits = (m <= SORT_CAP);

    if (t < NPB) { cnt[t] = 0; lcur[t] = 0; }
    __syncthreads();

    if (fits) {
        for (int j = t; j < m; j += 512) {          // single coalesced global read
            int p = bedge[s + j];
            stage[j] = p;
            atomicAdd(&cnt[p >> 17], 1);
        }
    } else {
        for (int j = t; j < m; j += 512) atomicAdd(&cnt[bedge[s + j] >> 17], 1);
    }
    __syncthreads();

    if (t < NPB) sc[t] = cnt[t];
    __syncthreads();
    for (int off = 1; off < NPB; off <<= 1) {
        int u = 0;
        if (t < NPB && t >= off) u = sc[t - off];
        __syncthreads();
        if (t < NPB && t >= off) sc[t] += u;
        __syncthreads();
    }
    if (t < NPB) {
        int c = cnt[t];
        lstart[t] = sc[t] - c;
        int g = b * NPB + t;
        node_off[g] = s + sc[t] - c;                // padding nodes -> sentinel s+m
        if (g < N_NODES) dinv[g] = rsqrtf((float)c + 1.0f);   // +1 self-loop
    }
    __syncthreads();

    if (fits) {
        for (int j = t; j < m; j += 512) {          // scatter into compact L2-resident window
            int p = stage[j];
            int lc = p >> 17;
            int pos = lstart[lc] + atomicAdd(&lcur[lc], 1);
            sorted_row[s + pos] = p & 0x1FFFF;
        }
    } else {
        for (int j = t; j < m; j += 512) {
            int p = bedge[s + j];
            int lc = p >> 17;
            int pos = lstart[lc] + atomicAdd(&lcur[lc], 1);
            sorted_row[s + pos] = p & 0x1FFFF;
        }
    }
}

// ---------------- bf16 helpers ----------------
__device__ inline unsigned int packbf2(float lo, float hi) {   // RTNE
    unsigned int ul = __float_as_uint(lo);
    ul += 0x7FFFu + ((ul >> 16) & 1u);
    unsigned int uh = __float_as_uint(hi);
    uh += 0x7FFFu + ((uh >> 16) & 1u);
    return (ul >> 16) | (uh & 0xFFFF0000u);
}

__device__ inline void addrow(float* __restrict__ acc, uint4 u) {
    acc[0] += __uint_as_float(u.x << 16);
    acc[1] += __uint_as_float(u.x & 0xFFFF0000u);
    acc[2] += __uint_as_float(u.y << 16);
    acc[3] += __uint_as_float(u.y & 0xFFFF0000u);
    acc[4] += __uint_as_float(u.z << 16);
    acc[5] += __uint_as_float(u.z & 0xFFFF0000u);
    acc[6] += __uint_as_float(u.w << 16);
    acc[7] += __uint_as_float(u.w & 0xFFFF0000u);
}

// ---------------- layer 1 GEMM: hs1b = bf16((x @ W1) * dinv) ----------------
__global__ __launch_bounds__(256) void k_gemm1(const float* __restrict__ x,
                                               const float* __restrict__ W1,
                                               const float* __restrict__ dinv,
                                               unsigned int* __restrict__ hs1b) {
    __shared__ float Ws[64 * 64];
    __shared__ float Xs[64 * 65];
    const int tx = threadIdx.x;
    const int nodeBase = blockIdx.x * 64;

    for (int t = tx; t < 64 * 64; t += 256) Ws[t] = W1[t];

    for (int t = tx; t < 64 * 16; t += 256) {
        int r = t >> 4, c4 = t & 15;
        int g = nodeBase + r;
        float4 v = make_float4(0.f, 0.f, 0.f, 0.f);
        if (g < N_NODES) v = reinterpret_cast<const float4*>(x)[g * 16 + c4];
        float* p = &Xs[r * 65 + c4 * 4];
        p[0] = v.x; p[1] = v.y; p[2] = v.z; p[3] = v.w;
    }
    __syncthreads();

    const int nG = tx >> 4;
    const int cG = tx & 15;
    float acc[4][4] = {};
    for (int k = 0; k < 64; ++k) {
        float4 w = *reinterpret_cast<const float4*>(&Ws[k * 64 + cG * 4]);
#pragma unroll
        for (int i = 0; i < 4; ++i) {
            float xv = Xs[(nG * 4 + i) * 65 + k];
            acc[i][0] = fmaf(xv, w.x, acc[i][0]);
            acc[i][1] = fmaf(xv, w.y, acc[i][1]);
            acc[i][2] = fmaf(xv, w.z, acc[i][2]);
            acc[i][3] = fmaf(xv, w.w, acc[i][3]);
        }
    }

#pragma unroll
    for (int i = 0; i < 4; ++i) {
        int n = nodeBase + nG * 4 + i;
        if (n < N_NODES) {
            float dv = dinv[n];
            uint2 o;
            o.x = packbf2(acc[i][0] * dv, acc[i][1] * dv);
            o.y = packbf2(acc[i][2] * dv, acc[i][3] * dv);
            reinterpret_cast<uint2*>(hs1b)[n * 16 + cG] = o;
        }
    }
}

// ---- fused: agg = self+neighbors (bf16 gather); h1=relu(dinv*agg+b1);
//      s=h1@W2; hs2=s*dinv; partial += dinv^2*s.  8 lanes/node, 32 nodes/block ----
__global__ __launch_bounds__(256) void k_agg_l2(const int* __restrict__ node_off,
                                                const int* __restrict__ sorted_row,
                                                const unsigned int* __restrict__ hs1b,
                                                const float* __restrict__ W2,
                                                const float* __restrict__ b1,
                                                const float* __restrict__ dinv,
                                                float* __restrict__ hs2,
                                                float* __restrict__ partials) {
    __shared__ float W2s[64 * NOUT];
    __shared__ float b1s[64];
    __shared__ float pacc[8];
    const int tx = threadIdx.x;
    for (int t = tx; t < 64 * NOUT; t += 256) W2s[t] = W2[t];
    if (tx < 64) b1s[tx] = b1[tx];
    if (tx < 8) pacc[tx] = 0.f;
    __syncthreads();

    const int node = (blockIdx.x * 256 + tx) >> 3;   // exact: N_NODES = 3125*32
    const int l = tx & 7;                            // lane owns channels l*8..l*8+7
    const int s = node_off[node], e = node_off[node + 1];
    const uint4* h4 = reinterpret_cast<const uint4*>(hs1b);   // 8 uint4 per 64-ch row

    float acc[8] = {};
    addrow(acc, h4[node * 8 + l]);                   // self-loop term
    int j = s;
    for (; j + 4 <= e; j += 4) {                     // 4 independent 16B gathers in flight
        int r0 = sorted_row[j],     r1 = sorted_row[j + 1];
        int r2 = sorted_row[j + 2], r3 = sorted_row[j + 3];
        uint4 a = h4[r0 * 8 + l];
        uint4 b = h4[r1 * 8 + l];
        uint4 c = h4[r2 * 8 + l];
        uint4 d = h4[r3 * 8 + l];
        addrow(acc, a); addrow(acc, b); addrow(acc, c); addrow(acc, d);
    }
    for (; j < e; ++j) addrow(acc, h4[sorted_row[j] * 8 + l]);

    const float dv = dinv[node];
    float sj[NOUT] = {};
#pragma unroll
    for (int i = 0; i < 8; ++i) {
        float hv = fmaxf(fmaf(dv, acc[i], b1s[l * 8 + i]), 0.f);
#pragma unroll
        for (int q = 0; q < NOUT; ++q) sj[q] = fmaf(hv, W2s[(l * 8 + i) * NOUT + q], sj[q]);
    }
#pragma unroll
    for (int q = 0; q < NOUT; ++q) {                 // reduce over the node's 8 lanes
        sj[q] += __shfl_xor(sj[q], 1, 64);
        sj[q] += __shfl_xor(sj[q], 2, 64);
        sj[q] += __shfl_xor(sj[q], 4, 64);
    }
    if (l == 0) {
        float4 o0 = make_float4(sj[0] * dv, sj[1] * dv, sj[2] * dv, sj[3] * dv);
        reinterpret_cast<float4*>(hs2)[node * 2] = o0;
        reinterpret_cast<float2*>(hs2)[node * 4 + 2] = make_float2(sj[4] * dv, sj[5] * dv);
        float sc = dv * dv;
#pragma unroll
        for (int q = 0; q < NOUT; ++q) atomicAdd(&pacc[q], sj[q] * sc);
    }
    __syncthreads();
    if (tx < NOUT) partials[blockIdx.x * 8 + tx] = pacc[tx];
}

// ---- edge-stream W-term: partial += dinv[col] * hs2[row], zero atomics ----
__global__ __launch_bounds__(256) void k_wsum(const int* __restrict__ row,
                                              const int* __restrict__ col,
                                              const float* __restrict__ dinv,
                                              const float* __restrict__ hs2,
                                              float* __restrict__ partials) {
    float a0 = 0.f, a1 = 0.f, a2 = 0.f, a3 = 0.f, a4 = 0.f, a5 = 0.f;
    for (int e = blockIdx.x * 256 + threadIdx.x; e < N_EDGES; e += WSB * 256) {
        int r = row[e], c = col[e];
        float dv = dinv[c];
        float4 h0 = reinterpret_cast<const float4*>(hs2)[r * 2];
        float2 h1 = reinterpret_cast<const float2*>(hs2)[r * 4 + 2];
        a0 = fmaf(dv, h0.x, a0);
        a1 = fmaf(dv, h0.y, a1);
        a2 = fmaf(dv, h0.z, a2);
        a3 = fmaf(dv, h0.w, a3);
        a4 = fmaf(dv, h1.x, a4);
        a5 = fmaf(dv, h1.y, a5);
    }
    __shared__ float wred[4][8];
    const int tx = threadIdx.x, lane = tx & 63, w = tx >> 6;
    float v[NOUT] = {a0, a1, a2, a3, a4, a5};
#pragma unroll
    for (int j = 0; j < NOUT; ++j) {
        float u = v[j];
        u += __shfl_xor(u, 1, 64);
        u += __shfl_xor(u, 2, 64);
        u += __shfl_xor(u, 4, 64);
        u += __shfl_xor(u, 8, 64);
        u += __shfl_xor(u, 16, 64);
        u += __shfl_xor(u, 32, 64);
        if (lane == 0) wred[w][j] = u;
    }
    __syncthreads();
    if (tx < NOUT)
        partials[(AGB + blockIdx.x) * 8 + tx] = wred[0][tx] + wred[1][tx] + wred[2][tx] + wred[3][tx];
}

// ---------------- final reduction over all partial groups ----------------
__global__ __launch_bounds__(256) void k_reduce2(const float* __restrict__ partials,
                                                 const float* __restrict__ b2,
                                                 float* __restrict__ out) {
    __shared__ float s[256];
    for (int j = 0; j < NOUT; ++j) {
        float a = 0.f;
        for (int p = threadIdx.x; p < NPART; p += 256) a += partials[p * 8 + j];
        s[threadIdx.x] = a;
        __syncthreads();
        for (int off = 128; off > 0; off >>= 1) {
            if (threadIdx.x < off) s[threadIdx.x] += s[threadIdx.x + off];
            __syncthreads();
        }
        if (threadIdx.x == 0) out[j] = b2[j] + s[0] * (1.0f / N_NODES);
        __syncthreads();
    }
}

extern "C" void kernel_launch(void* const* d_in, const int* in_sizes, int n_in,
                              void* d_out, int out_size, void* d_ws, size_t ws_size,
                              hipStream_t stream) {
    const float* x  = (const float*)d_in[0];
    const int*   ei = (const int*)d_in[1];
    const float* W1 = (const float*)d_in[2];
    const float* b1 = (const float*)d_in[3];
    const float* W2 = (const float*)d_in[4];
    const float* b2 = (const float*)d_in[5];
    float* out = (float*)d_out;

    // layout (words, all 16B-aligned)
    unsigned int* hs1b = (unsigned int*)d_ws;           // 3,200,000 (N x 64 bf16)
    float* dinv      = (float*)(hs1b + 3200000);        // 100,352
    float* hs2       = dinv + 100352;                   // 800,000 (N x 8)
    float* partials  = hs2 + 800000;                    // 33,280 (NPART*8 = 33,192 used)
    int*   gcounts   = (int*)(partials + 33280);        // 512
    int*   bbase     = gcounts + 512;                   // 512
    int*   gcursor   = bbase + 512;                     // 512
    int*   node_off  = gcursor + 512;                   // 100,160 (NBUK*NPB+pad)
    int*   sorted_row= node_off + 100160;               // 3,200,000
    int*   bedge     = sorted_row + 3200000;            // 3,200,000

    const int* row = ei;              // sources
    const int* col = ei + N_EDGES;    // targets

    // build bucketed, then per-node-sorted edge list; dinv
    k_zero512<<<1, 512, 0, stream>>>(gcounts);
    k_coarse_hist<<<1024, 256, 0, stream>>>(col, gcounts);
    k_coarse_scan<<<1, 512, 0, stream>>>(gcounts, bbase, gcursor);
    k_partition<<<PNB, 512, 0, stream>>>(row, col, gcursor, bedge);
    k_bucket_sort<<<NBUK, 512, 0, stream>>>(bbase, bedge, dinv, node_off, sorted_row);

    // layer 1 GEMM (bf16 output)
    k_gemm1<<<(N_NODES + 63) / 64, 256, 0, stream>>>(x, W1, dinv, hs1b);

    // fused aggregation + layer 2 + self-term partials
    k_agg_l2<<<AGB, 256, 0, stream>>>(node_off, sorted_row, hs1b, W2, b1, dinv, hs2, partials);

    // edge-stream W-term
    k_wsum<<<WSB, 256, 0, stream>>>(row, col, dinv, hs2, partials);

    k_reduce2<<<1, 256, 0, stream>>>(partials, b2, out);
}

// Round 7
// 179.807 us; speedup vs baseline: 9.4146x; 1.2217x over previous
//
#include <hip/hip_runtime.h>

#define N_NODES 100000
#define N_EDGES 3200000
#define NOUT 6

#define NPB 256                                   // nodes per bucket
#define NBUK ((N_NODES + NPB - 1) / NPB)          // 391
#define CAP 12288                                 // fixed bucket capacity (mean 8184, sigma~90)
#define PCHUNK 4096                               // edges per partition block
#define PNB ((N_EDGES + PCHUNK - 1) / PCHUNK)     // 782
#define SORT_CAP 10240                            // LDS stage capacity
#define AGB (N_NODES / 32)                        // 3125 blocks, 32 nodes each (8 lanes/node)
#define NPART (2 * AGB)                           // agg partials + wsum partials

typedef __attribute__((ext_vector_type(2))) float v2f;

// ---------------- init per-bucket cursors to b*CAP ----------------
__global__ __launch_bounds__(512) void k_initcur(int* __restrict__ gcursor) {
    int t = threadIdx.x;
    if (t < NBUK) gcursor[t] = t * CAP;
}

// ---------------- LDS-staged bucket partition: bedge[p] = (localcol<<17)|row ----------------
__global__ __launch_bounds__(512) void k_partition(const int* __restrict__ row,
                                                   const int* __restrict__ col,
                                                   int* __restrict__ gcursor,
                                                   int* __restrict__ bedge) {
    __shared__ int hist[512];
    __shared__ int lstart[512];
    __shared__ int lcur[512];
    __shared__ int gbase[512];
    __shared__ int sscan[512];
    __shared__ int stage[PCHUNK];
    __shared__ unsigned short stageb[PCHUNK];

    const int t = threadIdx.x;
    const int c0 = blockIdx.x * PCHUNK;
    int cnt = N_EDGES - c0; if (cnt > PCHUNK) cnt = PCHUNK;

    hist[t] = 0; lcur[t] = 0;
    __syncthreads();

    int myp[8]; int myb[8];
#pragma unroll
    for (int i = 0; i < 8; ++i) {
        int p = i * 512 + t;
        myb[i] = -1;
        if (p < cnt) {
            int e = c0 + p;
            int c = col[e], r = row[e];
            int b = c >> 8;
            myp[i] = ((c & 255) << 17) | r;
            myb[i] = b;
            atomicAdd(&hist[b], 1);
        }
    }
    __syncthreads();

    int hv = hist[t];
    sscan[t] = hv;
    __syncthreads();
    for (int off = 1; off < 512; off <<= 1) {
        int u = (t >= off) ? sscan[t - off] : 0;
        __syncthreads();
        sscan[t] += u;
        __syncthreads();
    }
    lstart[t] = sscan[t] - hv;
    if (t < NBUK && hv > 0) gbase[t] = atomicAdd(&gcursor[t], hv);
    __syncthreads();

#pragma unroll
    for (int i = 0; i < 8; ++i) {
        if (myb[i] >= 0) {
            int pos = lstart[myb[i]] + atomicAdd(&lcur[myb[i]], 1);
            stage[pos] = myp[i];
            stageb[pos] = (unsigned short)myb[i];
        }
    }
    __syncthreads();

    for (int p = t; p < cnt; p += 512) {
        int b = stageb[p];
        int dst = gbase[b] + p - lstart[b];
        if (dst < (b + 1) * CAP) bedge[dst] = stage[p];   // overflow guard (never for this input)
    }
}

// ---- per-bucket counting sort -> sorted_row + node offsets (b*257 layout) + dinv ----
__global__ __launch_bounds__(512) void k_bucket_sort(const int* __restrict__ gcursor,
                                                     const int* __restrict__ bedge,
                                                     float* __restrict__ dinv,
                                                     int* __restrict__ node_off,
                                                     int* __restrict__ sorted_row) {
    __shared__ int cnt[NPB];
    __shared__ int lstart[NPB];
    __shared__ int lcur[NPB];
    __shared__ int sc[NPB];
    __shared__ int stage[SORT_CAP];

    const int t = threadIdx.x;
    const int b = blockIdx.x;
    const int s = b * CAP;
    int m = gcursor[b] - s; if (m > CAP) m = CAP;
    const bool fits = (m <= SORT_CAP);

    if (t < NPB) { cnt[t] = 0; lcur[t] = 0; }
    __syncthreads();

    if (fits) {
        for (int j = t; j < m; j += 512) {          // single coalesced global read
            int p = bedge[s + j];
            stage[j] = p;
            atomicAdd(&cnt[p >> 17], 1);
        }
    } else {
        for (int j = t; j < m; j += 512) atomicAdd(&cnt[bedge[s + j] >> 17], 1);
    }
    __syncthreads();

    if (t < NPB) sc[t] = cnt[t];
    __syncthreads();
    for (int off = 1; off < NPB; off <<= 1) {
        int u = 0;
        if (t < NPB && t >= off) u = sc[t - off];
        __syncthreads();
        if (t < NPB && t >= off) sc[t] += u;
        __syncthreads();
    }
    if (t < NPB) {
        int c = cnt[t];
        lstart[t] = sc[t] - c;
        node_off[b * 257 + t] = s + sc[t] - c;
        int g = b * NPB + t;
        if (g < N_NODES) dinv[g] = rsqrtf((float)c + 1.0f);   // +1 self-loop
    }
    if (t == 256) node_off[b * 257 + 256] = s + m;            // bucket end sentinel
    __syncthreads();

    if (fits) {
        for (int j = t; j < m; j += 512) {          // scatter into compact window
            int p = stage[j];
            int lc = p >> 17;
            int pos = lstart[lc] + atomicAdd(&lcur[lc], 1);
            sorted_row[s + pos] = p & 0x1FFFF;
        }
    } else {
        for (int j = t; j < m; j += 512) {
            int p = bedge[s + j];
            int lc = p >> 17;
            int pos = lstart[lc] + atomicAdd(&lcur[lc], 1);
            sorted_row[s + pos] = p & 0x1FFFF;
        }
    }
}

// ---------------- layer 1 GEMM: hs1b = fp8_e4m3((x @ W1) * dinv) ----------------
__global__ __launch_bounds__(256) void k_gemm1(const float* __restrict__ x,
                                               const float* __restrict__ W1,
                                               const float* __restrict__ dinv,
                                               unsigned int* __restrict__ hs1b) {
    __shared__ float Ws[64 * 64];
    __shared__ float Xs[64 * 65];
    const int tx = threadIdx.x;
    const int nodeBase = blockIdx.x * 64;

    for (int t = tx; t < 64 * 64; t += 256) Ws[t] = W1[t];

    for (int t = tx; t < 64 * 16; t += 256) {
        int r = t >> 4, c4 = t & 15;
        int g = nodeBase + r;
        float4 v = make_float4(0.f, 0.f, 0.f, 0.f);
        if (g < N_NODES) v = reinterpret_cast<const float4*>(x)[g * 16 + c4];
        float* p = &Xs[r * 65 + c4 * 4];
        p[0] = v.x; p[1] = v.y; p[2] = v.z; p[3] = v.w;
    }
    __syncthreads();

    const int nG = tx >> 4;
    const int cG = tx & 15;
    float acc[4][4] = {};
    for (int k = 0; k < 64; ++k) {
        float4 w = *reinterpret_cast<const float4*>(&Ws[k * 64 + cG * 4]);
#pragma unroll
        for (int i = 0; i < 4; ++i) {
            float xv = Xs[(nG * 4 + i) * 65 + k];
            acc[i][0] = fmaf(xv, w.x, acc[i][0]);
            acc[i][1] = fmaf(xv, w.y, acc[i][1]);
            acc[i][2] = fmaf(xv, w.z, acc[i][2]);
            acc[i][3] = fmaf(xv, w.w, acc[i][3]);
        }
    }

#pragma unroll
    for (int i = 0; i < 4; ++i) {
        int n = nodeBase + nG * 4 + i;
        if (n < N_NODES) {
            float dv = dinv[n];
            int u = __builtin_amdgcn_cvt_pk_fp8_f32(acc[i][0] * dv, acc[i][1] * dv, 0, false);
            u = __builtin_amdgcn_cvt_pk_fp8_f32(acc[i][2] * dv, acc[i][3] * dv, u, true);
            hs1b[n * 16 + cG] = (unsigned int)u;   // bytes = channels 4*cG..4*cG+3
        }
    }
}

// ---------------- fp8 row-add: 8 channels from one uint2 ----------------
__device__ inline void addrow8(float* __restrict__ acc, uint2 u) {
    v2f p0 = __builtin_amdgcn_cvt_pk_f32_fp8((int)u.x, false);
    v2f p1 = __builtin_amdgcn_cvt_pk_f32_fp8((int)u.x, true);
    v2f p2 = __builtin_amdgcn_cvt_pk_f32_fp8((int)u.y, false);
    v2f p3 = __builtin_amdgcn_cvt_pk_f32_fp8((int)u.y, true);
    acc[0] += p0.x; acc[1] += p0.y; acc[2] += p1.x; acc[3] += p1.y;
    acc[4] += p2.x; acc[5] += p2.y; acc[6] += p3.x; acc[7] += p3.y;
}

// ---- fused: agg = self+neighbors (fp8 gather); h1=relu(dinv*agg+b1);
//      s=h1@W2; hs2=s*dinv (8-padded); partial += dinv^2*s.  8 lanes/node ----
__global__ __launch_bounds__(256) void k_agg_l2(const int* __restrict__ node_off,
                                                const int* __restrict__ sorted_row,
                                                const unsigned int* __restrict__ hs1b,
                                                const float* __restrict__ W2,
                                                const float* __restrict__ b1,
                                                const float* __restrict__ dinv,
                                                float* __restrict__ hs2,
                                                float* __restrict__ partials) {
    __shared__ float W2s[64 * NOUT];
    __shared__ float b1s[64];
    __shared__ float pacc[8];
    const int tx = threadIdx.x;
    for (int t = tx; t < 64 * NOUT; t += 256) W2s[t] = W2[t];
    if (tx < 64) b1s[tx] = b1[tx];
    if (tx < 8) pacc[tx] = 0.f;
    __syncthreads();

    const int node = (blockIdx.x * 256 + tx) >> 3;   // exact: N_NODES = 3125*32
    const int l = tx & 7;                            // lane owns channels l*8..l*8+7
    const int idx = (node >> 8) * 257 + (node & 255);
    const int s = node_off[idx], e = node_off[idx + 1];
    const uint2* h8 = reinterpret_cast<const uint2*>(hs1b);   // 8B = 8 fp8 channels

    float acc[8] = {};
    addrow8(acc, h8[node * 8 + l]);                  // self-loop term
    int j = s;
    for (; j + 4 <= e; j += 4) {                     // 4 independent 64B-line gathers in flight
        int r0 = sorted_row[j],     r1 = sorted_row[j + 1];
        int r2 = sorted_row[j + 2], r3 = sorted_row[j + 3];
        uint2 a = h8[r0 * 8 + l];
        uint2 b = h8[r1 * 8 + l];
        uint2 c = h8[r2 * 8 + l];
        uint2 d = h8[r3 * 8 + l];
        addrow8(acc, a); addrow8(acc, b); addrow8(acc, c); addrow8(acc, d);
    }
    for (; j < e; ++j) addrow8(acc, h8[sorted_row[j] * 8 + l]);

    const float dv = dinv[node];
    float sj[NOUT] = {};
#pragma unroll
    for (int i = 0; i < 8; ++i) {
        float hv = fmaxf(fmaf(dv, acc[i], b1s[l * 8 + i]), 0.f);
#pragma unroll
        for (int q = 0; q < NOUT; ++q) sj[q] = fmaf(hv, W2s[(l * 8 + i) * NOUT + q], sj[q]);
    }
#pragma unroll
    for (int q = 0; q < NOUT; ++q) {                 // reduce over the node's 8 lanes
        sj[q] += __shfl_xor(sj[q], 1, 64);
        sj[q] += __shfl_xor(sj[q], 2, 64);
        sj[q] += __shfl_xor(sj[q], 4, 64);
    }
    if (l == 0) {
        float4 o0 = make_float4(sj[0] * dv, sj[1] * dv, sj[2] * dv, sj[3] * dv);
        float4 o1 = make_float4(sj[4] * dv, sj[5] * dv, 0.f, 0.f);   // pad channels zeroed
        reinterpret_cast<float4*>(hs2)[node * 2] = o0;
        reinterpret_cast<float4*>(hs2)[node * 2 + 1] = o1;
        float sc = dv * dv;
#pragma unroll
        for (int q = 0; q < NOUT; ++q) atomicAdd(&pacc[q], sj[q] * sc);
    }
    __syncthreads();
    if (tx < NOUT) partials[blockIdx.x * 8 + tx] = pacc[tx];
}

// ---- W-term over sorted CSR: partial += dinv[c] * sum_{r in adj(c)} hs2[r] ----
__global__ __launch_bounds__(256) void k_wsum2(const int* __restrict__ node_off,
                                               const int* __restrict__ sorted_row,
                                               const float* __restrict__ dinv,
                                               const float* __restrict__ hs2,
                                               float* __restrict__ partials) {
    const int tx = threadIdx.x;
    const int node = (blockIdx.x * 256 + tx) >> 3;
    const int l = tx & 7;
    const int idx = (node >> 8) * 257 + (node & 255);
    const int s = node_off[idx], e = node_off[idx + 1];

    float a = 0.f;
    int j = s;
    for (; j + 4 <= e; j += 4) {
        int r0 = sorted_row[j],     r1 = sorted_row[j + 1];
        int r2 = sorted_row[j + 2], r3 = sorted_row[j + 3];
        float f0 = hs2[r0 * 8 + l];
        float f1 = hs2[r1 * 8 + l];
        float f2 = hs2[r2 * 8 + l];
        float f3 = hs2[r3 * 8 + l];
        a += (f0 + f1) + (f2 + f3);
    }
    for (; j < e; ++j) a += hs2[sorted_row[j] * 8 + l];
    a *= dinv[node];

    a += __shfl_xor(a, 8, 64);
    a += __shfl_xor(a, 16, 64);
    a += __shfl_xor(a, 32, 64);
    __shared__ float wred[4][8];
    const int lane = tx & 63, w = tx >> 6;
    if (lane < 8) wred[w][lane] = a;
    __syncthreads();
    if (tx < 8)
        partials[(AGB + blockIdx.x) * 8 + tx] = wred[0][tx] + wred[1][tx] + wred[2][tx] + wred[3][tx];
}

// ---------------- final reduction over all partial groups ----------------
__global__ __launch_bounds__(256) void k_reduce2(const float* __restrict__ partials,
                                                 const float* __restrict__ b2,
                                                 float* __restrict__ out) {
    __shared__ float s[256];
    for (int j = 0; j < NOUT; ++j) {
        float a = 0.f;
        for (int p = threadIdx.x; p < NPART; p += 256) a += partials[p * 8 + j];
        s[threadIdx.x] = a;
        __syncthreads();
        for (int off = 128; off > 0; off >>= 1) {
            if (threadIdx.x < off) s[threadIdx.x] += s[threadIdx.x + off];
            __syncthreads();
        }
        if (threadIdx.x == 0) out[j] = b2[j] + s[0] * (1.0f / N_NODES);
        __syncthreads();
    }
}

extern "C" void kernel_launch(void* const* d_in, const int* in_sizes, int n_in,
                              void* d_out, int out_size, void* d_ws, size_t ws_size,
                              hipStream_t stream) {
    const float* x  = (const float*)d_in[0];
    const int*   ei = (const int*)d_in[1];
    const float* W1 = (const float*)d_in[2];
    const float* b1 = (const float*)d_in[3];
    const float* W2 = (const float*)d_in[4];
    const float* b2 = (const float*)d_in[5];
    float* out = (float*)d_out;

    // layout (32-bit words, every region 16B-aligned)
    unsigned int* hs1b = (unsigned int*)d_ws;           // 1,600,000  (N x 64 fp8)
    float* dinv      = (float*)(hs1b + 1600000);        // 100,352
    float* hs2       = dinv + 100352;                   // 800,000   (N x 8)
    float* partials  = hs2 + 800000;                    // 50,176    (NPART*8 = 50,000 used)
    int*   gcursor   = (int*)(partials + 50176);        // 512
    int*   node_off  = gcursor + 512;                   // 100,864   (NBUK*257 = 100,487 used)
    int*   sorted_row= node_off + 100864;               // 4,804,608 (NBUK*CAP)
    int*   bedge     = sorted_row + 4804608;            // 4,804,608

    const int* row = ei;              // sources
    const int* col = ei + N_EDGES;    // targets

    // build bucketed, then per-node-sorted edge list; dinv
    k_initcur<<<1, 512, 0, stream>>>(gcursor);
    k_partition<<<PNB, 512, 0, stream>>>(row, col, gcursor, bedge);
    k_bucket_sort<<<NBUK, 512, 0, stream>>>(gcursor, bedge, dinv, node_off, sorted_row);

    // layer 1 GEMM (fp8 output)
    k_gemm1<<<(N_NODES + 63) / 64, 256, 0, stream>>>(x, W1, dinv, hs1b);

    // fused aggregation + layer 2 + self-term partials
    k_agg_l2<<<AGB, 256, 0, stream>>>(node_off, sorted_row, hs1b, W2, b1, dinv, hs2, partials);

    // W-term over sorted CSR
    k_wsum2<<<AGB, 256, 0, stream>>>(node_off, sorted_row, dinv, hs2, partials);

    k_reduce2<<<1, 256, 0, stream>>>(partials, b2, out);
}